// Round 14
// baseline (173.960 us; speedup 1.0000x reference)
//
#include <hip/hip_runtime.h>

#define NV 2708
#define INC 1433
#define XCOLS 1472        // padded K-dim for proj (23*64)
#define UDIM 2752         // padded U dims (43*64)
#define PSTR 2728         // pbuf stride in shorts
#define BSTR 2752
#define SLAB ((size_t)(2752*64))   // fp32 partial slab
#define MWPR 88
#define NSP 4             // proj split-K chunks (K-chunk 384; last 320)
#define NSU 11            // gemmG split-K chunks (2752 = 10*256 + 192)

typedef __attribute__((ext_vector_type(8))) short bf16x8;
typedef __attribute__((ext_vector_type(4))) float f32x4;
typedef __attribute__((ext_vector_type(4))) unsigned short u16x4;

__device__ __forceinline__ unsigned short f2bf(float f){
  union { float f; unsigned int i; } v; v.f = f;
  return (unsigned short)((v.i + 0x7fffu + ((v.i >> 16) & 1u)) >> 16);  // RNE
}

// ====== convert_all: A bitmask ONLY (X/W/U all consumed as fp32 directly) ===
__global__ __launch_bounds__(256) void convert_all(
    const int* __restrict__ A, unsigned int* __restrict__ Abits)
{
  const int i = blockIdx.x;            // < NV
  const int tid = threadIdx.x;
  const int lane = tid & 63, wave = tid >> 6;
  const int* arow = A + (size_t)i*NV;
  unsigned int* drow = Abits + (size_t)i*MWPR;
  for (int g = wave; g < 11; g += 4){
    int base = g*256 + lane*4;
    int4 v = make_int4(0,0,0,0);
    if (base < NV) v = *(const int4*)(arow + base);   // base<=2704 -> +3 in bounds
    unsigned long long m0 = __ballot(v.x != 0);
    unsigned long long m1 = __ballot(v.y != 0);
    unsigned long long m2 = __ballot(v.z != 0);
    unsigned long long m3 = __ballot(v.w != 0);
    if (lane < 8){
      unsigned long long mm = (lane < 2) ? m0 : (lane < 4) ? m1 : (lane < 6) ? m2 : m3;
      drow[g*8 + lane] = (lane & 1) ? (unsigned int)(mm >> 32) : (unsigned int)mm;
    }
  }
}

// ===== proj: partials of {K,Q,V} = X @ W^T, staged DIRECTLY from fp32. ======
// grid (86,4,3). 32-row m-tiles, LDS-staged A+B with in-register f2bf
// (bit-identical to the old Xbf/Wbf path; cols >= INC and rows >= NV are 0).
// X rows are only 4B-aligned (INC odd) -> scalar dword loads; each 32B line
// is reused 8x within the wave, L1 absorbs it.
__global__ __launch_bounds__(256) void proj(
    const float* __restrict__ X,
    const float* __restrict__ WK, const float* __restrict__ WQ,
    const float* __restrict__ WV,
    float* __restrict__ part)
{
  __shared__ __align__(16) unsigned short At[32*72];
  __shared__ __align__(16) unsigned short Bt[64*72];
  const int tid = threadIdx.x;
  const int lane = tid & 63, wave = tid >> 6, quad = lane >> 4, lr = lane & 15;
  const int m0 = blockIdx.x * 32;
  const int s  = blockIdx.y, z = blockIdx.z;
  const int kbeg = s * 384, kend = min(kbeg + 384, XCOLS);  // last chunk 320
  const int wm = (wave & 1) * 16, wn = (wave >> 1) * 32;
  const float* Wz = (z == 0) ? WK : (z == 1) ? WQ : WV;
  const int ar = tid >> 3, aseg = tid & 7;      // A: row 0..31, 8-col seg
  const int br = tid >> 2, bseg = tid & 3;      // B: row 0..63, 16-col seg
  const int grow = m0 + ar;
  const float* xr = X + (size_t)grow*INC;       // valid only if grow < NV
  const float* wr = Wz + (size_t)br*INC;
  f32x4 acc[2] = {};

  for (int k0 = kbeg; k0 < kend; k0 += 64){
    {                                           // ---- A stage (X fp32)
      int c = k0 + aseg*8;
      bf16x8 hv;
      if (grow < NV && c < INC){
        if (c + 8 <= INC){
          #pragma unroll
          for (int j = 0; j < 8; j++) hv[j] = (short)f2bf(xr[c + j]);
        } else {
          #pragma unroll
          for (int j = 0; j < 8; j++)
            hv[j] = (c + j < INC) ? (short)f2bf(xr[c + j]) : (short)0;
        }
      } else {
        #pragma unroll
        for (int j = 0; j < 8; j++) hv[j] = 0;
      }
      *(bf16x8*)&At[ar*72 + aseg*8] = hv;
    }
    {                                           // ---- B stage (W fp32)
      int c = k0 + bseg*16;
      bf16x8 h0, h1;
      if (c + 16 <= INC){
        #pragma unroll
        for (int j = 0; j < 8; j++) h0[j] = (short)f2bf(wr[c + j]);
        #pragma unroll
        for (int j = 0; j < 8; j++) h1[j] = (short)f2bf(wr[c + 8 + j]);
      } else {
        #pragma unroll
        for (int j = 0; j < 8; j++)
          h0[j] = (c + j < INC) ? (short)f2bf(wr[c + j]) : (short)0;
        #pragma unroll
        for (int j = 0; j < 8; j++)
          h1[j] = (c + 8 + j < INC) ? (short)f2bf(wr[c + 8 + j]) : (short)0;
      }
      *(bf16x8*)&Bt[br*72 + bseg*16]     = h0;
      *(bf16x8*)&Bt[br*72 + bseg*16 + 8] = h1;
    }
    __syncthreads();
    #pragma unroll
    for (int ks = 0; ks < 2; ks++){
      bf16x8 af = *(const bf16x8*)&At[(wm + lr)*72 + ks*32 + quad*8];
      bf16x8 bv[2];
      #pragma unroll
      for (int t = 0; t < 2; t++)
        bv[t] = *(const bf16x8*)&Bt[(wn + t*16 + lr)*72 + ks*32 + quad*8];
      #pragma unroll
      for (int t = 0; t < 2; t++)
        acc[t] = __builtin_amdgcn_mfma_f32_16x16x32_bf16(af, bv[t], acc[t], 0, 0, 0);
    }
    __syncthreads();
  }
  float* dst = part + (size_t)(z*NSP + s) * SLAB;
  #pragma unroll
  for (int t = 0; t < 2; t++)
    #pragma unroll
    for (int e = 0; e < 4; e++)
      dst[(size_t)(m0 + wm + quad*4 + e)*64 + wn + t*16 + lr] = acc[t][e];
}

// K16f frag-linear ; QT16 [c][m] ; VTf frag-linear. grid (688, 3).
__global__ __launch_bounds__(256) void reduce_proj(
    const float* __restrict__ part, unsigned short* __restrict__ K16f,
    unsigned short* __restrict__ QT16, unsigned short* __restrict__ VTf)
{
  int idx = blockIdx.x*256 + threadIdx.x;       // < 2752*64
  int z = blockIdx.y;
  int m = idx >> 6, c = idx & 63;
  const float* base = part + (size_t)z*NSP*SLAB + idx;
  float v = 0.f;
  #pragma unroll
  for (int s = 0; s < NSP; s++) v += base[s*SLAB];
  unsigned short h = (m < NV) ? f2bf(v) : (unsigned short)0;
  if (z == 0){
    if (m < 2720) K16f[((m>>4)*2 + (c>>5))*512 + (m&15)*32 + (c&31)] = h;
  } else if (z == 1){
    QT16[(size_t)c*BSTR + m] = h;
  } else {
    if (m < 2720) VTf[(m>>5)*2048 + c*32 + (m&31)] = h;
  }
}

// ===== gemmG: partials of G = U^T @ Q. grid (86, 11). ======================
// A staged from fp32 U with in-kernel transpose (U rows ARE 16B-aligned:
// NV*4 = 10832 B = 677*16). B = QT16 [c][k]. K-chunk 256.
__global__ __launch_bounds__(256) void gemmG(
    const float* __restrict__ U, const unsigned short* __restrict__ Bcm,
    float* __restrict__ part)
{
  __shared__ __align__(16) unsigned short At[32*72];
  __shared__ __align__(16) unsigned short Bt[64*72];
  const int tid = threadIdx.x;
  const int lane = tid & 63, wave = tid >> 6, quad = lane >> 4, lr = lane & 15;
  const int m0 = blockIdx.x * 32;
  const int s  = blockIdx.y;
  const int kbeg = s * 256, kend = min(kbeg + 256, UDIM);   // last chunk 192
  const int wm = (wave & 1) * 16, wn = (wave >> 1) * 32;
  const int ml = (tid & 7)*4, kr = tid >> 3;    // m-chunk 0..28, k-row 0..31
  const int bc = tid >> 2, bseg = tid & 3;
  const bool mok = (m0 + ml) < NV;              // m-chunks never straddle NV (2708%4==0)
  f32x4 acc[2] = {};

  for (int k0 = kbeg; k0 < kend; k0 += 64){
    #pragma unroll
    for (int e = 0; e < 2; e++){
      int kl = kr + e*32;
      int row = k0 + kl;
      float4 v = make_float4(0.f,0.f,0.f,0.f);
      if (row < NV && mok) v = *(const float4*)(U + (size_t)row*NV + m0 + ml);
      At[(ml+0)*72 + kl] = f2bf(v.x);
      At[(ml+1)*72 + kl] = f2bf(v.y);
      At[(ml+2)*72 + kl] = f2bf(v.z);
      At[(ml+3)*72 + kl] = f2bf(v.w);
    }
    {
      const unsigned short* b = Bcm + (size_t)bc*BSTR + k0 + bseg*16;
      *(bf16x8*)&Bt[bc*72 + bseg*16]     = *(const bf16x8*)(b);
      *(bf16x8*)&Bt[bc*72 + bseg*16 + 8] = *(const bf16x8*)(b + 8);
    }
    __syncthreads();
    #pragma unroll
    for (int ks = 0; ks < 2; ks++){
      bf16x8 af = *(const bf16x8*)&At[(wm + lr)*72 + ks*32 + quad*8];
      bf16x8 bv[2];
      #pragma unroll
      for (int t = 0; t < 2; t++)
        bv[t] = *(const bf16x8*)&Bt[(wn + t*16 + lr)*72 + ks*32 + quad*8];
      #pragma unroll
      for (int t = 0; t < 2; t++)
        acc[t] = __builtin_amdgcn_mfma_f32_16x16x32_bf16(af, bv[t], acc[t], 0, 0, 0);
    }
    __syncthreads();
  }
  float* dst = part + (size_t)s * SLAB;
  #pragma unroll
  for (int t = 0; t < 2; t++)
    #pragma unroll
    for (int e = 0; e < 4; e++)
      dst[(size_t)(m0 + wm + quad*4 + e)*64 + wn + t*16 + lr] = acc[t][e];
}

// G2T16[c][m] = bf16(G[m][c] * lmbd[m]/64), zero pads. grid 688.
__global__ __launch_bounds__(256) void reduce_g(
    const float* __restrict__ part, const float* __restrict__ lm,
    unsigned short* __restrict__ G2T)
{
  int idx = blockIdx.x*256 + threadIdx.x;
  int m = idx >> 6, c = idx & 63;
  const float* base = part + idx;
  float v = 0.f;
  #pragma unroll
  for (int s = 0; s < NSU; s++) v += base[s*SLAB];
  unsigned short h = 0;
  if (m < NV) h = f2bf(v * lm[m] * (1.0f/64.0f));
  G2T[(size_t)c*BSTR + m] = h;
}

// ====== fused: F = U@G2 (phase 0) + |F K^T| -> masked exp + row-sum -> P V ==
// 16 rows/block, 512 threads (8 waves), 170 blocks. Phase 0 reads fp32 U rows
// directly (in-register f2bf; k >= NV garbage annihilated by G2T zero pads).
__global__ __launch_bounds__(512) void fused_attn(
    const float* __restrict__ U, const unsigned short* __restrict__ G2T,
    const unsigned short* __restrict__ K16f,
    const unsigned int* __restrict__ Abits, const unsigned short* __restrict__ VTf,
    float* __restrict__ Hout)
{
  __shared__ __align__(16) unsigned short pbuf[16*PSTR];   // 87.3 KB (phase0: fpart)
  __shared__ __align__(16) unsigned short fbuf[16*64];     // 2 KB
  __shared__ unsigned int mrow[16*MWPR];                   // 5.6 KB
  __shared__ float swave[8][16];
  __shared__ float rinv[16];
  __shared__ __align__(16) float obuf[4][256];             // 4 KB
  const int tid  = threadIdx.x;
  const int lane = tid & 63, wave = tid >> 6;
  const int quad = lane >> 4, lr = lane & 15;
  const int i0 = blockIdx.x * 16;

  // ---- phase 0: F[16][64] = U[i0:i0+16][:] @ G2 ----
  float* fpart = (float*)pbuf;                 // [8][4][256] fp32 = 32 KB
  {
    f32x4 facc[4] = {};
    const bool rok = (i0 + lr) < NV;
    const float* urow = U + (size_t)(i0 + lr)*NV;
    for (int ks = wave; ks < 86; ks += 8){
      const int k0 = ks*32;
      const int kc = k0 + quad*8;
      bf16x8 af;
      if (!rok){
        #pragma unroll
        for (int j = 0; j < 8; j++) af[j] = 0;
      } else if (kc + 7 < NV){
        float4 a = *(const float4*)(urow + kc);
        float4 b = *(const float4*)(urow + kc + 4);
        af[0] = (short)f2bf(a.x); af[1] = (short)f2bf(a.y);
        af[2] = (short)f2bf(a.z); af[3] = (short)f2bf(a.w);
        af[4] = (short)f2bf(b.x); af[5] = (short)f2bf(b.y);
        af[6] = (short)f2bf(b.z); af[7] = (short)f2bf(b.w);
      } else {
        #pragma unroll
        for (int j = 0; j < 8; j++){
          int col = kc + j;
          af[j] = (col < NV) ? (short)f2bf(urow[col]) : (short)0;
        }
      }
      #pragma unroll
      for (int n = 0; n < 4; n++){
        bf16x8 bv = *(const bf16x8*)(G2T + (size_t)(n*16 + lr)*BSTR + k0 + quad*8);
        facc[n] = __builtin_amdgcn_mfma_f32_16x16x32_bf16(af, bv, facc[n], 0, 0, 0);
      }
    }
    #pragma unroll
    for (int n = 0; n < 4; n++)
      *(f32x4*)&fpart[(wave*4 + n)*256 + lane*4] = facc[n];
  }
  for (int idx = tid; idx < 16*MWPR; idx += 512){
    int r = idx / MWPR;
    unsigned int v = 0;
    if (i0 + r < NV) v = Abits[(size_t)(i0 + r)*MWPR + (idx - r*MWPR)];
    mrow[idx] = v;
  }
  __syncthreads();
  // reduce 8 wave-partials -> fbuf bf16 (C layout: row=(l>>4)*4+e, col=n*16+(l&15))
  for (int idx = tid; idx < 1024; idx += 512){
    int n = idx >> 8, l4 = idx & 255;
    float v = 0.f;
    #pragma unroll
    for (int w = 0; w < 8; w++) v += fpart[(w*4 + n)*256 + l4];
    int l = l4 >> 2, e = l4 & 3;
    fbuf[((l >> 4)*4 + e)*64 + n*16 + (l & 15)] = f2bf(v);
  }
  __syncthreads();

  // ---- phase A: S = |F K^T| masked exp, P in pbuf, row-sums ----
  const bf16x8 af0 = *(const bf16x8*)&fbuf[lr*64 + quad*8];
  const bf16x8 af1 = *(const bf16x8*)&fbuf[lr*64 + 32 + quad*8];
  float psum[4] = {0.f, 0.f, 0.f, 0.f};
  {
    int t = wave;
    const unsigned short* kb = K16f + t*1024 + lr*32 + quad*8;
    bf16x8 b0 = *(const bf16x8*)(kb);
    bf16x8 b1 = *(const bf16x8*)(kb + 512);
    while (t < 170){
      int tn = t + 8;
      bf16x8 n0 = b0, n1 = b1;
      if (tn < 170){
        const unsigned short* nb = K16f + tn*1024 + lr*32 + quad*8;
        n0 = *(const bf16x8*)(nb);
        n1 = *(const bf16x8*)(nb + 512);
      }
      f32x4 sv0 = {}, sv1 = {};
      sv0 = __builtin_amdgcn_mfma_f32_16x16x32_bf16(af0, b0, sv0, 0, 0, 0);
      sv1 = __builtin_amdgcn_mfma_f32_16x16x32_bf16(af1, b1, sv1, 0, 0, 0);
      f32x4 sv = sv0 + sv1;
      {
        int col = t*16 + lr;
        int ss = col & 255, ll = ss >> 2;
        int wsh = (col >> 8)*8 + (ss & 3)*2 + (ll >> 5);
        int bit = ll & 31;
        #pragma unroll
        for (int e = 0; e < 4; e++){
          int r = quad*4 + e;
          float p = 0.f;
          if ((mrow[r*MWPR + wsh] >> bit) & 1u) p = __expf(fabsf(sv[e]));
          psum[e] += p;
          pbuf[r*PSTR + col] = f2bf(p);
        }
      }
      b0 = n0; b1 = n1; t = tn;
    }
  }
  #pragma unroll
  for (int e = 0; e < 4; e++){
    float v = psum[e];
    #pragma unroll
    for (int o = 1; o <= 8; o <<= 1) v += __shfl_xor(v, o, 64);
    if (lr == 0) swave[wave][quad*4 + e] = v;
  }
  __syncthreads();
  if (tid < 16){
    float s = 0.f;
    #pragma unroll
    for (int w = 0; w < 8; w++) s += swave[w][tid];
    rinv[tid] = (s > 0.f) ? (1.f/s) : 0.f;
  }
  __syncthreads();

  // ---- phase C: O = P @ V. wave&3 -> col group, wave>>2 -> kt half. ----
  const int c0 = (wave & 3) * 16;
  const int ktbeg = (wave >> 2) ? 43 : 0;
  const int ktend = (wave >> 2) ? 85 : 43;
  f32x4 acc = {};
  {
    bf16x8 bv = *(const bf16x8*)&VTf[ktbeg*2048 + (c0 + lr)*32 + quad*8];
    for (int kt = ktbeg; kt < ktend; kt++){
      bf16x8 bn = bv;
      if (kt + 1 < ktend) bn = *(const bf16x8*)&VTf[(kt+1)*2048 + (c0 + lr)*32 + quad*8];
      bf16x8 af = *(const bf16x8*)&pbuf[lr*PSTR + kt*32 + quad*8];
      acc = __builtin_amdgcn_mfma_f32_16x16x32_bf16(af, bv, acc, 0, 0, 0);
      bv = bn;
    }
  }
  if (wave >= 4) *(f32x4*)&obuf[wave & 3][lane*4] = acc;
  __syncthreads();
  if (wave < 4){
    f32x4 o = *(const f32x4*)&obuf[wave][lane*4];
    acc += o;
    #pragma unroll
    for (int e = 0; e < 4; e++){
      int r = quad*4 + e;
      int i = i0 + r;
      if (i < NV) Hout[(size_t)i*64 + c0 + lr] = acc[e] * rinv[r];
    }
  }
}

extern "C" void kernel_launch(void* const* d_in, const int* in_sizes, int n_in,
                              void* d_out, int out_size, void* d_ws, size_t ws_size,
                              hipStream_t stream){
  (void)in_sizes; (void)n_in; (void)out_size; (void)ws_size;
  const float* X  = (const float*)d_in[0];
  const int*   A  = (const int*)d_in[1];
  const float* U  = (const float*)d_in[2];
  const float* WK = (const float*)d_in[3];
  const float* WQ = (const float*)d_in[4];
  const float* WV = (const float*)d_in[5];
  const float* lm = (const float*)d_in[6];

  char* ws = (char*)d_ws;
  size_t off = 0;
  auto alloc = [&](size_t bytes){ size_t o = off; off = (off + bytes + 255) & ~(size_t)255; return o; };
  float*          part = (float*)(ws + alloc(12*SLAB*4));                      // 8.45 MB (K/Q/V; 0-10 reused for G)
  unsigned short* K16f = (unsigned short*)(ws + alloc((size_t)170*1024*2));
  unsigned short* QT16 = (unsigned short*)(ws + alloc((size_t)64*BSTR*2));
  unsigned short* G2T  = (unsigned short*)(ws + alloc((size_t)64*BSTR*2));
  unsigned short* VTf  = (unsigned short*)(ws + alloc((size_t)85*2048*2));
  unsigned int*   Abits= (unsigned int*)(ws + alloc((size_t)NV*MWPR*4));
  // total ~12 MB

  convert_all<<<dim3(NV), 256, 0, stream>>>(A, Abits);
  proj<<<dim3(86, NSP, 3), 256, 0, stream>>>(X, WK, WQ, WV, part);
  reduce_proj<<<dim3(688, 3), 256, 0, stream>>>(part, K16f, QT16, VTf);
  gemmG<<<dim3(86, NSU), 256, 0, stream>>>(U, QT16, part);        // G partials
  reduce_g<<<dim3(688), 256, 0, stream>>>(part, lm, G2T);
  fused_attn<<<dim3(170), 512, 0, stream>>>(U, G2T, K16f, Abits, VTf, (float*)d_out);
}